// Round 46
// baseline (418.575 us; speedup 1.0000x reference)
//
#include <hip/hip_runtime.h>

#define DH 48
#define NXCD 8

// ---------------- edge-index layout detection ----------------
// flag=1 -> buffer is raw int64 (odd int32 words all zero); flag=0 -> int32.

__global__ __launch_bounds__(256) void detect_k(const int* __restrict__ ei32, int nsamp, int* __restrict__ flag) {
    __shared__ int any;
    if (threadIdx.x == 0) any = 0;
    __syncthreads();
    int acc = 0;
    for (int k = threadIdx.x; k < nsamp; k += 256) acc |= ei32[2 * k + 1];
    if (acc) atomicOr(&any, 1);
    __syncthreads();
    if (threadIdx.x == 0) flag[0] = any ? 0 : 1;
}

__device__ __forceinline__ int clampi(int v, int lo, int hi) {
    return v < lo ? lo : (v > hi ? hi : v);
}
__device__ __forceinline__ int esrc(const int* ei, int e, int E, int is64) {
    return is64 ? ei[2 * e] : ei[e];
}
__device__ __forceinline__ int edst(const int* ei, int e, int E, int is64) {
    return is64 ? ei[2 * (E + e)] : ei[E + e];
}

// ---------------- CSR build (primary path) ----------------

__global__ __launch_bounds__(256) void hist_k(const int* __restrict__ ei, int* __restrict__ deg, int E, int N,
                                              const int* __restrict__ flag) {
    int is64 = flag[0];
    int e = blockIdx.x * 256 + threadIdx.x;
    if (e < E) {
        int d = clampi(edst(ei, e, E, is64), 0, N - 1);
        atomicAdd(&deg[d], 1);
    }
}

__global__ __launch_bounds__(256) void scanA_k(const int* __restrict__ deg, int* __restrict__ chunk_scan,
                                               int* __restrict__ blk_sums, int n) {
    __shared__ int ps[256];
    int b = blockIdx.x, t = threadIdx.x;
    int base = b * 512;
    int i0 = base + 2 * t, i1 = base + 2 * t + 1;
    int v0 = (i0 < n) ? deg[i0] : 0;
    int v1 = (i1 < n) ? deg[i1] : 0;
    ps[t] = v0 + v1;
    __syncthreads();
    for (int off = 1; off < 256; off <<= 1) {
        int x = (t >= off) ? ps[t - off] : 0;
        __syncthreads();
        ps[t] += x;
        __syncthreads();
    }
    int excl = (t > 0) ? ps[t - 1] : 0;
    if (i0 < n) chunk_scan[i0] = excl + v0;
    if (i1 < n) chunk_scan[i1] = excl + v0 + v1;
    if (t == 255) blk_sums[b] = ps[255];
}

__global__ __launch_bounds__(256) void scanB_k(const int* __restrict__ blk_sums, int* __restrict__ blk_scan, int nblk) {
    __shared__ int ps[256];
    int t = threadIdx.x;
    ps[t] = (t < nblk) ? blk_sums[t] : 0;
    __syncthreads();
    for (int off = 1; off < 256; off <<= 1) {
        int x = (t >= off) ? ps[t - off] : 0;
        __syncthreads();
        ps[t] += x;
        __syncthreads();
    }
    if (t < nblk) blk_scan[t] = ps[t];
}

__global__ __launch_bounds__(256) void scanC_k(const int* __restrict__ chunk_scan, const int* __restrict__ blk_scan,
                                               int* __restrict__ row_ptr, int n) {
    int i = blockIdx.x * 256 + threadIdx.x;
    if (i == 0) row_ptr[0] = 0;
    if (i < n) {
        int b = i >> 9;
        int off = (b > 0) ? blk_scan[b - 1] : 0;
        row_ptr[i + 1] = chunk_scan[i] + off;
    }
}

// XCD-grouped fill (round 44: fill 130->82us, WRITE 107->72MB -- partial win;
// residual writeback is L2 eviction by streaming edge reads, not mapping).

__global__ __launch_bounds__(256) void fill_xcd_k(const int* __restrict__ ei, const int* __restrict__ row_ptr,
                                                  int* __restrict__ cnt, int* __restrict__ col, int E, int N,
                                                  const int* __restrict__ flag, int blocks_per_xcd) {
    int is64 = flag[0];
    int xcd = blockIdx.x % NXCD;
    int sub = blockIdx.x / NXCD;
    int lo = (int)(((long long)xcd * N) / NXCD);
    int hi = (int)(((long long)(xcd + 1) * N) / NXCD);
    int stride = blocks_per_xcd * 256;
    for (int e = sub * 256 + threadIdx.x; e < E; e += stride) {
        int d = clampi(edst(ei, e, E, is64), 0, N - 1);
        if (d < lo || d >= hi) continue;
        int s = clampi(esrc(ei, e, E, is64), 0, N - 1);
        int p = row_ptr[d] + atomicAdd(&cnt[d], 1);
        p = clampi(p, 0, E - 1);
        col[p] = s;
    }
}

// ---------------- raw pull aggregation: agg[node] = sum_{e in CSR[node]} xin[col[e]] ----------------
// 16 lanes per node; lane j owns features {j, j+16, j+32}.

__global__ __launch_bounds__(256) void agg_pull_k(const int* __restrict__ row_ptr, const int* __restrict__ col,
                                                  const float* __restrict__ xin, float* __restrict__ aggout,
                                                  int n, int E) {
    int t = blockIdx.x * 256 + threadIdx.x;
    int node = t >> 4;
    int j = t & 15;
    if (node >= n) return;
    int e0 = clampi(row_ptr[node], 0, E);
    int e1 = clampi(row_ptr[node + 1], e0, E);
    float a0 = 0.f, a1 = 0.f, a2 = 0.f;
    for (int e = e0; e < e1; ++e) {
        int s = col[e];
        const float* p = xin + (size_t)s * DH;
        a0 += p[j];
        a1 += p[j + 16];
        a2 += p[j + 32];
    }
    float* o = aggout + (size_t)node * DH;
    o[j] = a0;
    o[j + 16] = a1;
    o[j + 32] = a2;
}

// ---------------- scatter aggregation (fallback path, float atomics) ----------------

__global__ __launch_bounds__(256) void scatter_k(const int* __restrict__ ei, const float* __restrict__ xin,
                                                 float* __restrict__ aggout, int E, int N,
                                                 const int* __restrict__ flag) {
    int is64 = flag[0];
    int t = blockIdx.x * 256 + threadIdx.x;
    int e = t >> 4;
    int j = t & 15;
    if (e >= E) return;
    int s = clampi(esrc(ei, e, E, is64), 0, N - 1);
    int d = clampi(edst(ei, e, E, is64), 0, N - 1);
    const float* p = xin + (size_t)s * DH;
    float* o = aggout + (size_t)d * DH;
    atomicAdd(&o[j], p[j]);
    atomicAdd(&o[j + 16], p[j + 16]);
    atomicAdd(&o[j + 32], p[j + 32]);
}

// ---------------- fused per-node transform, 4 threads/node ----------------
// Round 44: 1-thread/node version was occupancy-bound (391 blocks, 16.5% occ,
// VALUBusy 13.6%). Thread j of a node computes outputs [12j,12j+12): grid x4,
// acc 48->12 regs. Same per-output summation order -> bitwise-identical result.
// Threads of one node share a wave (t&3 grouping) -> in-place layer-2 safe:
// all agg-row loads precede the slice stores in wave-ordered program order.

template <int RELU>
__global__ __launch_bounds__(256) void dual_transform4_k(const float* agg, const float* __restrict__ xin,
                                                         const float* __restrict__ w_rel,
                                                         const float* __restrict__ w_root,
                                                         const float* __restrict__ bias, float* outp, int n) {
    int t = blockIdx.x * 256 + threadIdx.x;
    int node = t >> 2;
    int j = t & 3;
    if (node >= n) return;
    const float4* ap = reinterpret_cast<const float4*>(agg + (size_t)node * DH);
    const float4* xp = reinterpret_cast<const float4*>(xin + (size_t)node * DH);
    float acc[12];
#pragma unroll
    for (int c = 0; c < 12; c++) acc[c] = bias[j * 12 + c];
#pragma unroll
    for (int q = 0; q < 12; q++) {
        float4 a4 = ap[q];
        float4 x4 = xp[q];
        float as[4] = {a4.x, a4.y, a4.z, a4.w};
        float xs[4] = {x4.x, x4.y, x4.z, x4.w};
#pragma unroll
        for (int c4 = 0; c4 < 4; c4++) {
            int k = q * 4 + c4;
            const float4* wr4 = reinterpret_cast<const float4*>(w_rel + k * DH + j * 12);
            const float4* wo4 = reinterpret_cast<const float4*>(w_root + k * DH + j * 12);
            float ak = as[c4], xk = xs[c4];
#pragma unroll
            for (int m = 0; m < 3; m++) {
                float4 wr = wr4[m];
                float4 wo = wo4[m];
                acc[m * 4 + 0] = fmaf(ak, wr.x, fmaf(xk, wo.x, acc[m * 4 + 0]));
                acc[m * 4 + 1] = fmaf(ak, wr.y, fmaf(xk, wo.y, acc[m * 4 + 1]));
                acc[m * 4 + 2] = fmaf(ak, wr.z, fmaf(xk, wo.z, acc[m * 4 + 2]));
                acc[m * 4 + 3] = fmaf(ak, wr.w, fmaf(xk, wo.w, acc[m * 4 + 3]));
            }
        }
    }
    float4* op = reinterpret_cast<float4*>(outp + (size_t)node * DH + j * 12);
#pragma unroll
    for (int m = 0; m < 3; m++) {
        float4 v;
        v.x = RELU ? fmaxf(acc[m * 4 + 0], 0.f) : acc[m * 4 + 0];
        v.y = RELU ? fmaxf(acc[m * 4 + 1], 0.f) : acc[m * 4 + 1];
        v.z = RELU ? fmaxf(acc[m * 4 + 2], 0.f) : acc[m * 4 + 2];
        v.w = RELU ? fmaxf(acc[m * 4 + 3], 0.f) : acc[m * 4 + 3];
        op[m] = v;
    }
}

// ---------------- launch ----------------

extern "C" void kernel_launch(void* const* d_in, const int* in_sizes, int n_in,
                              void* d_out, int out_size, void* d_ws, size_t ws_size,
                              hipStream_t stream) {
    const float* x       = (const float*)d_in[0];
    const int*   ei      = (const int*)d_in[1];
    const float* w_rel1  = (const float*)d_in[2];
    const float* w_root1 = (const float*)d_in[3];
    const float* b1      = (const float*)d_in[4];
    const float* w_rel2  = (const float*)d_in[5];
    const float* w_root2 = (const float*)d_in[6];
    const float* b2      = (const float*)d_in[7];
    float* out = (float*)d_out;

    int N = in_sizes[0] / DH;   // 100000
    int E = in_sizes[1] / 2;    // 1600000

    auto align256 = [](size_t v) { return (v + 255) & ~(size_t)255; };

    // --- workspace plan ---
    size_t sz_deg   = align256((size_t)N * 4);
    size_t sz_rp    = align256((size_t)(N + 1) * 4);
    size_t sz_small = align256(1024);
    size_t sz_flag  = align256(256);
    size_t sz_col   = align256((size_t)E * 4);
    size_t sz_h     = align256((size_t)N * DH * 4);

    size_t need_fallback = sz_flag + sz_h;
    size_t need_primary  = 4 * sz_deg + sz_rp + 2 * sz_small + sz_flag + sz_col + sz_h;

    if (ws_size < need_fallback) return;  // cannot compute safely; fail validation cleanly

    int ebk  = (E + 255) / 256;
    int nbk4 = (N * 4 + 255) / 256;
    int nbk  = (N + 255) / 256;
    int abk  = (N * 16 + 255) / 256;
    int sbk  = (E * 16 + 255) / 256;
    int nblk = (N + 511) / 512;  // must be <= 256 for scanB

    if (ws_size >= need_primary && nblk <= 256) {
        // ---- primary: CSR + pull (no float atomics) ----
        char* p = (char*)d_ws;
        int* deg        = (int*)p; p += sz_deg;
        int* cnt        = (int*)p; p += sz_deg;
        int* chunk_scan = (int*)p; p += sz_deg;
        int* row_ptr    = (int*)p; p += sz_rp;
        int* blk_sums   = (int*)p; p += sz_small;
        int* blk_scan   = (int*)p; p += sz_small;
        int* flag       = (int*)p; p += sz_flag;
        int* col        = (int*)p; p += sz_col;
        float* h        = (float*)p; p += sz_h;

        hipMemsetAsync(deg, 0, (size_t)N * 4, stream);
        hipMemsetAsync(cnt, 0, (size_t)N * 4, stream);

        detect_k<<<1, 256, 0, stream>>>(ei, 4096, flag);
        hist_k<<<ebk, 256, 0, stream>>>(ei, deg, E, N, flag);
        scanA_k<<<nblk, 256, 0, stream>>>(deg, chunk_scan, blk_sums, N);
        scanB_k<<<1, 256, 0, stream>>>(blk_sums, blk_scan, nblk);
        scanC_k<<<nbk, 256, 0, stream>>>(chunk_scan, blk_scan, row_ptr, N);

        int bpx = 128;  // blocks per XCD group; grid = 8*128 = 1024
        fill_xcd_k<<<NXCD * bpx, 256, 0, stream>>>(ei, row_ptr, cnt, col, E, N, flag, bpx);

        // layer 1: agg_raw(x) -> d_out; h = relu(d_out@w_rel1 + x@w_root1 + b1)
        agg_pull_k<<<abk, 256, 0, stream>>>(row_ptr, col, x, out, N, E);
        dual_transform4_k<1><<<nbk4, 256, 0, stream>>>(out, x, w_rel1, w_root1, b1, h, N);
        // layer 2: agg_raw(h) -> d_out; out = d_out@w_rel2 + h@w_root2 + b2 (in place)
        agg_pull_k<<<abk, 256, 0, stream>>>(row_ptr, col, h, out, N, E);
        dual_transform4_k<0><<<nbk4, 256, 0, stream>>>(out, h, w_rel2, w_root2, b2, out, N);
    } else {
        // ---- fallback: scatter atomics into d_out, only h in ws ----
        char* p = (char*)d_ws;
        int* flag = (int*)p; p += sz_flag;
        float* h  = (float*)p; p += sz_h;

        detect_k<<<1, 256, 0, stream>>>(ei, 4096, flag);

        hipMemsetAsync(out, 0, (size_t)N * DH * 4, stream);
        scatter_k<<<sbk, 256, 0, stream>>>(ei, x, out, E, N, flag);
        dual_transform4_k<1><<<nbk4, 256, 0, stream>>>(out, x, w_rel1, w_root1, b1, h, N);

        hipMemsetAsync(out, 0, (size_t)N * DH * 4, stream);
        scatter_k<<<sbk, 256, 0, stream>>>(ei, h, out, E, N, flag);
        dual_transform4_k<0><<<nbk4, 256, 0, stream>>>(out, h, w_rel2, w_root2, b2, out, N);
    }
}

// Round 47
// 413.868 us; speedup vs baseline: 1.0114x; 1.0114x over previous
//
#include <hip/hip_runtime.h>

#define DH 48
#define NXCD 8

// ---------------- edge-index layout detection ----------------
// flag=1 -> buffer is raw int64 (odd int32 words all zero); flag=0 -> int32.

__global__ __launch_bounds__(256) void detect_k(const int* __restrict__ ei32, int nsamp, int* __restrict__ flag) {
    __shared__ int any;
    if (threadIdx.x == 0) any = 0;
    __syncthreads();
    int acc = 0;
    for (int k = threadIdx.x; k < nsamp; k += 256) acc |= ei32[2 * k + 1];
    if (acc) atomicOr(&any, 1);
    __syncthreads();
    if (threadIdx.x == 0) flag[0] = any ? 0 : 1;
}

__device__ __forceinline__ int clampi(int v, int lo, int hi) {
    return v < lo ? lo : (v > hi ? hi : v);
}
__device__ __forceinline__ int esrc(const int* ei, int e, int E, int is64) {
    return is64 ? ei[2 * e] : ei[e];
}
__device__ __forceinline__ int edst(const int* ei, int e, int E, int is64) {
    return is64 ? ei[2 * (E + e)] : ei[E + e];
}

// ---------------- CSR build (primary path) ----------------

__global__ __launch_bounds__(256) void hist_k(const int* __restrict__ ei, int* __restrict__ deg, int E, int N,
                                              const int* __restrict__ flag) {
    int is64 = flag[0];
    int e = blockIdx.x * 256 + threadIdx.x;
    if (e < E) {
        int d = clampi(edst(ei, e, E, is64), 0, N - 1);
        atomicAdd(&deg[d], 1);
    }
}

__global__ __launch_bounds__(256) void scanA_k(const int* __restrict__ deg, int* __restrict__ chunk_scan,
                                               int* __restrict__ blk_sums, int n) {
    __shared__ int ps[256];
    int b = blockIdx.x, t = threadIdx.x;
    int base = b * 512;
    int i0 = base + 2 * t, i1 = base + 2 * t + 1;
    int v0 = (i0 < n) ? deg[i0] : 0;
    int v1 = (i1 < n) ? deg[i1] : 0;
    ps[t] = v0 + v1;
    __syncthreads();
    for (int off = 1; off < 256; off <<= 1) {
        int x = (t >= off) ? ps[t - off] : 0;
        __syncthreads();
        ps[t] += x;
        __syncthreads();
    }
    int excl = (t > 0) ? ps[t - 1] : 0;
    if (i0 < n) chunk_scan[i0] = excl + v0;
    if (i1 < n) chunk_scan[i1] = excl + v0 + v1;
    if (t == 255) blk_sums[b] = ps[255];
}

__global__ __launch_bounds__(256) void scanB_k(const int* __restrict__ blk_sums, int* __restrict__ blk_scan, int nblk) {
    __shared__ int ps[256];
    int t = threadIdx.x;
    ps[t] = (t < nblk) ? blk_sums[t] : 0;
    __syncthreads();
    for (int off = 1; off < 256; off <<= 1) {
        int x = (t >= off) ? ps[t - off] : 0;
        __syncthreads();
        ps[t] += x;
        __syncthreads();
    }
    if (t < nblk) blk_scan[t] = ps[t];
}

__global__ __launch_bounds__(256) void scanC_k(const int* __restrict__ chunk_scan, const int* __restrict__ blk_scan,
                                               int* __restrict__ row_ptr, int n) {
    int i = blockIdx.x * 256 + threadIdx.x;
    if (i == 0) row_ptr[0] = 0;
    if (i < n) {
        int b = i >> 9;
        int off = (b > 0) ? blk_scan[b - 1] : 0;
        row_ptr[i + 1] = chunk_scan[i] + off;
    }
}

// XCD-grouped fill. Round 46: 76us, FETCH 50MB (8x dst re-read, by design),
// WRITE 71MB (partial-line writebacks persist), occupancy 41%, 1.6TB/s ->
// parallelism-limited BW. bpx 128->256 to raise waves in flight.

__global__ __launch_bounds__(256) void fill_xcd_k(const int* __restrict__ ei, const int* __restrict__ row_ptr,
                                                  int* __restrict__ cnt, int* __restrict__ col, int E, int N,
                                                  const int* __restrict__ flag, int blocks_per_xcd) {
    int is64 = flag[0];
    int xcd = blockIdx.x % NXCD;
    int sub = blockIdx.x / NXCD;
    int lo = (int)(((long long)xcd * N) / NXCD);
    int hi = (int)(((long long)(xcd + 1) * N) / NXCD);
    int stride = blocks_per_xcd * 256;
    for (int e = sub * 256 + threadIdx.x; e < E; e += stride) {
        int d = clampi(edst(ei, e, E, is64), 0, N - 1);
        if (d < lo || d >= hi) continue;
        int s = clampi(esrc(ei, e, E, is64), 0, N - 1);
        int p = row_ptr[d] + atomicAdd(&cnt[d], 1);
        p = clampi(p, 0, E - 1);
        col[p] = s;
    }
}

// ---------------- raw pull aggregation: agg[node] = sum_{e in CSR[node]} xin[col[e]] ----------------
// 16 lanes per node; lane j owns features {j, j+16, j+32}.

__global__ __launch_bounds__(256) void agg_pull_k(const int* __restrict__ row_ptr, const int* __restrict__ col,
                                                  const float* __restrict__ xin, float* __restrict__ aggout,
                                                  int n, int E) {
    int t = blockIdx.x * 256 + threadIdx.x;
    int node = t >> 4;
    int j = t & 15;
    if (node >= n) return;
    int e0 = clampi(row_ptr[node], 0, E);
    int e1 = clampi(row_ptr[node + 1], e0, E);
    float a0 = 0.f, a1 = 0.f, a2 = 0.f;
    for (int e = e0; e < e1; ++e) {
        int s = col[e];
        const float* p = xin + (size_t)s * DH;
        a0 += p[j];
        a1 += p[j + 16];
        a2 += p[j + 32];
    }
    float* o = aggout + (size_t)node * DH;
    o[j] = a0;
    o[j + 16] = a1;
    o[j + 32] = a2;
}

// ---------------- scatter aggregation (fallback path, float atomics) ----------------

__global__ __launch_bounds__(256) void scatter_k(const int* __restrict__ ei, const float* __restrict__ xin,
                                                 float* __restrict__ aggout, int E, int N,
                                                 const int* __restrict__ flag) {
    int is64 = flag[0];
    int t = blockIdx.x * 256 + threadIdx.x;
    int e = t >> 4;
    int j = t & 15;
    if (e >= E) return;
    int s = clampi(esrc(ei, e, E, is64), 0, N - 1);
    int d = clampi(edst(ei, e, E, is64), 0, N - 1);
    const float* p = xin + (size_t)s * DH;
    float* o = aggout + (size_t)d * DH;
    atomicAdd(&o[j], p[j]);
    atomicAdd(&o[j + 16], p[j + 16]);
    atomicAdd(&o[j + 32], p[j + 32]);
}

// ---------------- fused per-node transform, 4 threads/node ----------------
// Round 46: dropped out of top-5 (<75us, was 82-83 at 16.5% occupancy) --
// occupancy fix confirmed directionally. 4 lanes/node read identical row
// addresses -> coalesced broadcast, no extra traffic.

template <int RELU>
__global__ __launch_bounds__(256) void dual_transform4_k(const float* agg, const float* __restrict__ xin,
                                                         const float* __restrict__ w_rel,
                                                         const float* __restrict__ w_root,
                                                         const float* __restrict__ bias, float* outp, int n) {
    int t = blockIdx.x * 256 + threadIdx.x;
    int node = t >> 2;
    int j = t & 3;
    if (node >= n) return;
    const float4* ap = reinterpret_cast<const float4*>(agg + (size_t)node * DH);
    const float4* xp = reinterpret_cast<const float4*>(xin + (size_t)node * DH);
    float acc[12];
#pragma unroll
    for (int c = 0; c < 12; c++) acc[c] = bias[j * 12 + c];
#pragma unroll
    for (int q = 0; q < 12; q++) {
        float4 a4 = ap[q];
        float4 x4 = xp[q];
        float as[4] = {a4.x, a4.y, a4.z, a4.w};
        float xs[4] = {x4.x, x4.y, x4.z, x4.w};
#pragma unroll
        for (int c4 = 0; c4 < 4; c4++) {
            int k = q * 4 + c4;
            const float4* wr4 = reinterpret_cast<const float4*>(w_rel + k * DH + j * 12);
            const float4* wo4 = reinterpret_cast<const float4*>(w_root + k * DH + j * 12);
            float ak = as[c4], xk = xs[c4];
#pragma unroll
            for (int m = 0; m < 3; m++) {
                float4 wr = wr4[m];
                float4 wo = wo4[m];
                acc[m * 4 + 0] = fmaf(ak, wr.x, fmaf(xk, wo.x, acc[m * 4 + 0]));
                acc[m * 4 + 1] = fmaf(ak, wr.y, fmaf(xk, wo.y, acc[m * 4 + 1]));
                acc[m * 4 + 2] = fmaf(ak, wr.z, fmaf(xk, wo.z, acc[m * 4 + 2]));
                acc[m * 4 + 3] = fmaf(ak, wr.w, fmaf(xk, wo.w, acc[m * 4 + 3]));
            }
        }
    }
    float4* op = reinterpret_cast<float4*>(outp + (size_t)node * DH + j * 12);
#pragma unroll
    for (int m = 0; m < 3; m++) {
        float4 v;
        v.x = RELU ? fmaxf(acc[m * 4 + 0], 0.f) : acc[m * 4 + 0];
        v.y = RELU ? fmaxf(acc[m * 4 + 1], 0.f) : acc[m * 4 + 1];
        v.z = RELU ? fmaxf(acc[m * 4 + 2], 0.f) : acc[m * 4 + 2];
        v.w = RELU ? fmaxf(acc[m * 4 + 3], 0.f) : acc[m * 4 + 3];
        op[m] = v;
    }
}

// ---------------- launch ----------------

extern "C" void kernel_launch(void* const* d_in, const int* in_sizes, int n_in,
                              void* d_out, int out_size, void* d_ws, size_t ws_size,
                              hipStream_t stream) {
    const float* x       = (const float*)d_in[0];
    const int*   ei      = (const int*)d_in[1];
    const float* w_rel1  = (const float*)d_in[2];
    const float* w_root1 = (const float*)d_in[3];
    const float* b1      = (const float*)d_in[4];
    const float* w_rel2  = (const float*)d_in[5];
    const float* w_root2 = (const float*)d_in[6];
    const float* b2      = (const float*)d_in[7];
    float* out = (float*)d_out;

    int N = in_sizes[0] / DH;   // 100000
    int E = in_sizes[1] / 2;    // 1600000

    auto align256 = [](size_t v) { return (v + 255) & ~(size_t)255; };

    // --- workspace plan ---
    size_t sz_deg   = align256((size_t)N * 4);
    size_t sz_rp    = align256((size_t)(N + 1) * 4);
    size_t sz_small = align256(1024);
    size_t sz_flag  = align256(256);
    size_t sz_col   = align256((size_t)E * 4);
    size_t sz_h     = align256((size_t)N * DH * 4);

    size_t need_fallback = sz_flag + sz_h;
    size_t need_primary  = 4 * sz_deg + sz_rp + 2 * sz_small + sz_flag + sz_col + sz_h;

    if (ws_size < need_fallback) return;  // cannot compute safely; fail validation cleanly

    int ebk  = (E + 255) / 256;
    int nbk4 = (N * 4 + 255) / 256;
    int nbk  = (N + 255) / 256;
    int abk  = (N * 16 + 255) / 256;
    int sbk  = (E * 16 + 255) / 256;
    int nblk = (N + 511) / 512;  // must be <= 256 for scanB

    if (ws_size >= need_primary && nblk <= 256) {
        // ---- primary: CSR + pull (no float atomics) ----
        char* p = (char*)d_ws;
        int* deg        = (int*)p; p += sz_deg;
        int* cnt        = (int*)p; p += sz_deg;
        int* chunk_scan = (int*)p; p += sz_deg;
        int* row_ptr    = (int*)p; p += sz_rp;
        int* blk_sums   = (int*)p; p += sz_small;
        int* blk_scan   = (int*)p; p += sz_small;
        int* flag       = (int*)p; p += sz_flag;
        int* col        = (int*)p; p += sz_col;
        float* h        = (float*)p; p += sz_h;

        hipMemsetAsync(deg, 0, (size_t)N * 4, stream);
        hipMemsetAsync(cnt, 0, (size_t)N * 4, stream);

        detect_k<<<1, 256, 0, stream>>>(ei, 4096, flag);
        hist_k<<<ebk, 256, 0, stream>>>(ei, deg, E, N, flag);
        scanA_k<<<nblk, 256, 0, stream>>>(deg, chunk_scan, blk_sums, N);
        scanB_k<<<1, 256, 0, stream>>>(blk_sums, blk_scan, nblk);
        scanC_k<<<nbk, 256, 0, stream>>>(chunk_scan, blk_scan, row_ptr, N);

        int bpx = 256;  // blocks per XCD group; grid = 8*256 = 2048 (round 46: 41% occ -> raise waves)
        fill_xcd_k<<<NXCD * bpx, 256, 0, stream>>>(ei, row_ptr, cnt, col, E, N, flag, bpx);

        // layer 1: agg_raw(x) -> d_out; h = relu(d_out@w_rel1 + x@w_root1 + b1)
        agg_pull_k<<<abk, 256, 0, stream>>>(row_ptr, col, x, out, N, E);
        dual_transform4_k<1><<<nbk4, 256, 0, stream>>>(out, x, w_rel1, w_root1, b1, h, N);
        // layer 2: agg_raw(h) -> d_out; out = d_out@w_rel2 + h@w_root2 + b2 (in place)
        agg_pull_k<<<abk, 256, 0, stream>>>(row_ptr, col, h, out, N, E);
        dual_transform4_k<0><<<nbk4, 256, 0, stream>>>(out, h, w_rel2, w_root2, b2, out, N);
    } else {
        // ---- fallback: scatter atomics into d_out, only h in ws ----
        char* p = (char*)d_ws;
        int* flag = (int*)p; p += sz_flag;
        float* h  = (float*)p; p += sz_h;

        detect_k<<<1, 256, 0, stream>>>(ei, 4096, flag);

        hipMemsetAsync(out, 0, (size_t)N * DH * 4, stream);
        scatter_k<<<sbk, 256, 0, stream>>>(ei, x, out, E, N, flag);
        dual_transform4_k<1><<<nbk4, 256, 0, stream>>>(out, x, w_rel1, w_root1, b1, h, N);

        hipMemsetAsync(out, 0, (size_t)N * DH * 4, stream);
        scatter_k<<<sbk, 256, 0, stream>>>(ei, h, out, E, N, flag);
        dual_transform4_k<0><<<nbk4, 256, 0, stream>>>(out, h, w_rel2, w_root2, b2, out, N);
    }
}

// Round 48
// 328.680 us; speedup vs baseline: 1.2735x; 1.2592x over previous
//
#include <hip/hip_runtime.h>

#define DH 48
#define NXCD 8

// ---------------- edge-index layout detection ----------------
// flag=1 -> buffer is raw int64 (odd int32 words all zero); flag=0 -> int32.

__global__ __launch_bounds__(256) void detect_k(const int* __restrict__ ei32, int nsamp, int* __restrict__ flag) {
    __shared__ int any;
    if (threadIdx.x == 0) any = 0;
    __syncthreads();
    int acc = 0;
    for (int k = threadIdx.x; k < nsamp; k += 256) acc |= ei32[2 * k + 1];
    if (acc) atomicOr(&any, 1);
    __syncthreads();
    if (threadIdx.x == 0) flag[0] = any ? 0 : 1;
}

__device__ __forceinline__ int clampi(int v, int lo, int hi) {
    return v < lo ? lo : (v > hi ? hi : v);
}
__device__ __forceinline__ int esrc(const int* ei, int e, int E, int is64) {
    return is64 ? ei[2 * e] : ei[e];
}
__device__ __forceinline__ int edst(const int* ei, int e, int E, int is64) {
    return is64 ? ei[2 * (E + e)] : ei[E + e];
}

// ---------------- CSR build (primary path) ----------------

__global__ __launch_bounds__(256) void hist_k(const int* __restrict__ ei, int* __restrict__ deg, int E, int N,
                                              const int* __restrict__ flag) {
    int is64 = flag[0];
    int e = blockIdx.x * 256 + threadIdx.x;
    if (e < E) {
        int d = clampi(edst(ei, e, E, is64), 0, N - 1);
        atomicAdd(&deg[d], 1);
    }
}

__global__ __launch_bounds__(256) void scanA_k(const int* __restrict__ deg, int* __restrict__ chunk_scan,
                                               int* __restrict__ blk_sums, int n) {
    __shared__ int ps[256];
    int b = blockIdx.x, t = threadIdx.x;
    int base = b * 512;
    int i0 = base + 2 * t, i1 = base + 2 * t + 1;
    int v0 = (i0 < n) ? deg[i0] : 0;
    int v1 = (i1 < n) ? deg[i1] : 0;
    ps[t] = v0 + v1;
    __syncthreads();
    for (int off = 1; off < 256; off <<= 1) {
        int x = (t >= off) ? ps[t - off] : 0;
        __syncthreads();
        ps[t] += x;
        __syncthreads();
    }
    int excl = (t > 0) ? ps[t - 1] : 0;
    if (i0 < n) chunk_scan[i0] = excl + v0;
    if (i1 < n) chunk_scan[i1] = excl + v0 + v1;
    if (t == 255) blk_sums[b] = ps[255];
}

__global__ __launch_bounds__(256) void scanB_k(const int* __restrict__ blk_sums, int* __restrict__ blk_scan, int nblk) {
    __shared__ int ps[256];
    int t = threadIdx.x;
    ps[t] = (t < nblk) ? blk_sums[t] : 0;
    __syncthreads();
    for (int off = 1; off < 256; off <<= 1) {
        int x = (t >= off) ? ps[t - off] : 0;
        __syncthreads();
        ps[t] += x;
        __syncthreads();
    }
    if (t < nblk) blk_scan[t] = ps[t];
}

__global__ __launch_bounds__(256) void scanC_k(const int* __restrict__ chunk_scan, const int* __restrict__ blk_scan,
                                               int* __restrict__ row_ptr, int n) {
    int i = blockIdx.x * 256 + threadIdx.x;
    if (i == 0) row_ptr[0] = 0;
    if (i < n) {
        int b = i >> 9;
        int off = (b > 0) ? blk_scan[b - 1] : 0;
        row_ptr[i + 1] = chunk_scan[i] + off;
    }
}

// XCD-grouped fill. Round 47: 71us @ 80% occupancy, 1.78TB/s on 126MB --
// near its structural traffic limit; further gains need rank-from-hist
// restructuring (deferred).

__global__ __launch_bounds__(256) void fill_xcd_k(const int* __restrict__ ei, const int* __restrict__ row_ptr,
                                                  int* __restrict__ cnt, int* __restrict__ col, int E, int N,
                                                  const int* __restrict__ flag, int blocks_per_xcd) {
    int is64 = flag[0];
    int xcd = blockIdx.x % NXCD;
    int sub = blockIdx.x / NXCD;
    int lo = (int)(((long long)xcd * N) / NXCD);
    int hi = (int)(((long long)(xcd + 1) * N) / NXCD);
    int stride = blocks_per_xcd * 256;
    for (int e = sub * 256 + threadIdx.x; e < E; e += stride) {
        int d = clampi(edst(ei, e, E, is64), 0, N - 1);
        if (d < lo || d >= hi) continue;
        int s = clampi(esrc(ei, e, E, is64), 0, N - 1);
        int p = row_ptr[d] + atomicAdd(&cnt[d], 1);
        p = clampi(p, 0, E - 1);
        col[p] = s;
    }
}

// ---------------- raw pull aggregation: agg[node] = sum_{e in CSR[node]} xin[col[e]] ----------------
// 16 lanes per node; lane j owns features {j, j+16, j+32}.

__global__ __launch_bounds__(256) void agg_pull_k(const int* __restrict__ row_ptr, const int* __restrict__ col,
                                                  const float* __restrict__ xin, float* __restrict__ aggout,
                                                  int n, int E) {
    int t = blockIdx.x * 256 + threadIdx.x;
    int node = t >> 4;
    int j = t & 15;
    if (node >= n) return;
    int e0 = clampi(row_ptr[node], 0, E);
    int e1 = clampi(row_ptr[node + 1], e0, E);
    float a0 = 0.f, a1 = 0.f, a2 = 0.f;
    for (int e = e0; e < e1; ++e) {
        int s = col[e];
        const float* p = xin + (size_t)s * DH;
        a0 += p[j];
        a1 += p[j + 16];
        a2 += p[j + 32];
    }
    float* o = aggout + (size_t)node * DH;
    o[j] = a0;
    o[j + 16] = a1;
    o[j + 32] = a2;
}

// ---------------- scatter aggregation (fallback path, float atomics) ----------------

__global__ __launch_bounds__(256) void scatter_k(const int* __restrict__ ei, const float* __restrict__ xin,
                                                 float* __restrict__ aggout, int E, int N,
                                                 const int* __restrict__ flag) {
    int is64 = flag[0];
    int t = blockIdx.x * 256 + threadIdx.x;
    int e = t >> 4;
    int j = t & 15;
    if (e >= E) return;
    int s = clampi(esrc(ei, e, E, is64), 0, N - 1);
    int d = clampi(edst(ei, e, E, is64), 0, N - 1);
    const float* p = xin + (size_t)s * DH;
    float* o = aggout + (size_t)d * DH;
    atomicAdd(&o[j], p[j]);
    atomicAdd(&o[j + 16], p[j + 16]);
    atomicAdd(&o[j + 32], p[j + 32]);
}

// ---------------- fused per-node transform, 4 threads/node + LDS weights ----------------
// Round 47: global-weight version 71us, occupancy 44%, VALUBusy 9% ->
// latency-bound on 288 float4 weight loads/thread. Stage w_rel+w_root+bias
// in LDS once per block (18.6KB -> still 8 blocks/CU). j-slices hit banks
// {0-3},{12-15},{24-27},{4-7}: conflict-free; same-j lanes broadcast.
// FMA order unchanged -> bitwise-identical output.

template <int RELU>
__global__ __launch_bounds__(256) void dual_transform4_k(const float* agg, const float* __restrict__ xin,
                                                         const float* __restrict__ w_rel,
                                                         const float* __restrict__ w_root,
                                                         const float* __restrict__ bias, float* outp, int n) {
    __shared__ float lwr[DH * DH];
    __shared__ float lwo[DH * DH];
    __shared__ float lb[DH];
    for (int i = threadIdx.x; i < DH * DH; i += 256) {
        lwr[i] = w_rel[i];
        lwo[i] = w_root[i];
    }
    if (threadIdx.x < DH) lb[threadIdx.x] = bias[threadIdx.x];
    __syncthreads();

    int t = blockIdx.x * 256 + threadIdx.x;
    int node = t >> 2;
    int j = t & 3;
    if (node >= n) return;
    const float4* ap = reinterpret_cast<const float4*>(agg + (size_t)node * DH);
    const float4* xp = reinterpret_cast<const float4*>(xin + (size_t)node * DH);
    float acc[12];
#pragma unroll
    for (int c = 0; c < 12; c++) acc[c] = lb[j * 12 + c];
#pragma unroll
    for (int q = 0; q < 12; q++) {
        float4 a4 = ap[q];
        float4 x4 = xp[q];
        float as[4] = {a4.x, a4.y, a4.z, a4.w};
        float xs[4] = {x4.x, x4.y, x4.z, x4.w};
#pragma unroll
        for (int c4 = 0; c4 < 4; c4++) {
            int k = q * 4 + c4;
            const float4* wr4 = reinterpret_cast<const float4*>(&lwr[k * DH + j * 12]);
            const float4* wo4 = reinterpret_cast<const float4*>(&lwo[k * DH + j * 12]);
            float ak = as[c4], xk = xs[c4];
#pragma unroll
            for (int m = 0; m < 3; m++) {
                float4 wr = wr4[m];
                float4 wo = wo4[m];
                acc[m * 4 + 0] = fmaf(ak, wr.x, fmaf(xk, wo.x, acc[m * 4 + 0]));
                acc[m * 4 + 1] = fmaf(ak, wr.y, fmaf(xk, wo.y, acc[m * 4 + 1]));
                acc[m * 4 + 2] = fmaf(ak, wr.z, fmaf(xk, wo.z, acc[m * 4 + 2]));
                acc[m * 4 + 3] = fmaf(ak, wr.w, fmaf(xk, wo.w, acc[m * 4 + 3]));
            }
        }
    }
    float4* op = reinterpret_cast<float4*>(outp + (size_t)node * DH + j * 12);
#pragma unroll
    for (int m = 0; m < 3; m++) {
        float4 v;
        v.x = RELU ? fmaxf(acc[m * 4 + 0], 0.f) : acc[m * 4 + 0];
        v.y = RELU ? fmaxf(acc[m * 4 + 1], 0.f) : acc[m * 4 + 1];
        v.z = RELU ? fmaxf(acc[m * 4 + 2], 0.f) : acc[m * 4 + 2];
        v.w = RELU ? fmaxf(acc[m * 4 + 3], 0.f) : acc[m * 4 + 3];
        op[m] = v;
    }
}

// ---------------- launch ----------------

extern "C" void kernel_launch(void* const* d_in, const int* in_sizes, int n_in,
                              void* d_out, int out_size, void* d_ws, size_t ws_size,
                              hipStream_t stream) {
    const float* x       = (const float*)d_in[0];
    const int*   ei      = (const int*)d_in[1];
    const float* w_rel1  = (const float*)d_in[2];
    const float* w_root1 = (const float*)d_in[3];
    const float* b1      = (const float*)d_in[4];
    const float* w_rel2  = (const float*)d_in[5];
    const float* w_root2 = (const float*)d_in[6];
    const float* b2      = (const float*)d_in[7];
    float* out = (float*)d_out;

    int N = in_sizes[0] / DH;   // 100000
    int E = in_sizes[1] / 2;    // 1600000

    auto align256 = [](size_t v) { return (v + 255) & ~(size_t)255; };

    // --- workspace plan ---
    size_t sz_deg   = align256((size_t)N * 4);
    size_t sz_rp    = align256((size_t)(N + 1) * 4);
    size_t sz_small = align256(1024);
    size_t sz_flag  = align256(256);
    size_t sz_col   = align256((size_t)E * 4);
    size_t sz_h     = align256((size_t)N * DH * 4);

    size_t need_fallback = sz_flag + sz_h;
    size_t need_primary  = 4 * sz_deg + sz_rp + 2 * sz_small + sz_flag + sz_col + sz_h;

    if (ws_size < need_fallback) return;  // cannot compute safely; fail validation cleanly

    int ebk  = (E + 255) / 256;
    int nbk4 = (N * 4 + 255) / 256;
    int nbk  = (N + 255) / 256;
    int abk  = (N * 16 + 255) / 256;
    int sbk  = (E * 16 + 255) / 256;
    int nblk = (N + 511) / 512;  // must be <= 256 for scanB

    if (ws_size >= need_primary && nblk <= 256) {
        // ---- primary: CSR + pull (no float atomics) ----
        char* p = (char*)d_ws;
        int* deg        = (int*)p; p += sz_deg;
        int* cnt        = (int*)p; p += sz_deg;
        int* chunk_scan = (int*)p; p += sz_deg;
        int* row_ptr    = (int*)p; p += sz_rp;
        int* blk_sums   = (int*)p; p += sz_small;
        int* blk_scan   = (int*)p; p += sz_small;
        int* flag       = (int*)p; p += sz_flag;
        int* col        = (int*)p; p += sz_col;
        float* h        = (float*)p; p += sz_h;

        hipMemsetAsync(deg, 0, (size_t)N * 4, stream);
        hipMemsetAsync(cnt, 0, (size_t)N * 4, stream);

        detect_k<<<1, 256, 0, stream>>>(ei, 4096, flag);
        hist_k<<<ebk, 256, 0, stream>>>(ei, deg, E, N, flag);
        scanA_k<<<nblk, 256, 0, stream>>>(deg, chunk_scan, blk_sums, N);
        scanB_k<<<1, 256, 0, stream>>>(blk_sums, blk_scan, nblk);
        scanC_k<<<nbk, 256, 0, stream>>>(chunk_scan, blk_scan, row_ptr, N);

        int bpx = 256;  // blocks per XCD group; grid = 8*256 = 2048
        fill_xcd_k<<<NXCD * bpx, 256, 0, stream>>>(ei, row_ptr, cnt, col, E, N, flag, bpx);

        // layer 1: agg_raw(x) -> d_out; h = relu(d_out@w_rel1 + x@w_root1 + b1)
        agg_pull_k<<<abk, 256, 0, stream>>>(row_ptr, col, x, out, N, E);
        dual_transform4_k<1><<<nbk4, 256, 0, stream>>>(out, x, w_rel1, w_root1, b1, h, N);
        // layer 2: agg_raw(h) -> d_out; out = d_out@w_rel2 + h@w_root2 + b2 (in place)
        agg_pull_k<<<abk, 256, 0, stream>>>(row_ptr, col, h, out, N, E);
        dual_transform4_k<0><<<nbk4, 256, 0, stream>>>(out, h, w_rel2, w_root2, b2, out, N);
    } else {
        // ---- fallback: scatter atomics into d_out, only h in ws ----
        char* p = (char*)d_ws;
        int* flag = (int*)p; p += sz_flag;
        float* h  = (float*)p; p += sz_h;

        detect_k<<<1, 256, 0, stream>>>(ei, 4096, flag);

        hipMemsetAsync(out, 0, (size_t)N * DH * 4, stream);
        scatter_k<<<sbk, 256, 0, stream>>>(ei, x, out, E, N, flag);
        dual_transform4_k<1><<<nbk4, 256, 0, stream>>>(out, x, w_rel1, w_root1, b1, h, N);

        hipMemsetAsync(out, 0, (size_t)N * DH * 4, stream);
        scatter_k<<<sbk, 256, 0, stream>>>(ei, h, out, E, N, flag);
        dual_transform4_k<0><<<nbk4, 256, 0, stream>>>(out, h, w_rel2, w_root2, b2, out, N);
    }
}